// Round 1
// baseline (92.476 us; speedup 1.0000x reference)
//
#include <hip/hip_runtime.h>
#include <math.h>

#define NB   2
#define NP   4096
#define KNN  32
#define DIMC 128
#define NROWS (NB*NP)          // 8192
#define MTOT  (NB*NP*KNN)      // 262144

static constexpr float R2 = (float)(0.2*0.2);

// ---------------- K0: ball query (one wave per point, ballot-ranked hits) ----------------
__global__ __launch_bounds__(256) void k_ballquery(const float* __restrict__ xyzp,
                                                   int* __restrict__ idx)
{
#pragma clang fp contract(off)
    const int w    = threadIdx.x >> 6;
    const int lane = threadIdx.x & 63;
    const int pt   = blockIdx.x * 4 + w;      // 0..8191
    const int b    = pt >> 12;
    const int i    = pt & (NP - 1);

    const float xi = xyzp[((size_t)b*NP + i)*4 + 0];
    const float yi = xyzp[((size_t)b*NP + i)*4 + 1];
    int* orow = idx + (size_t)pt * KNN;

    int cnt = 0;
    for (int chunk = 0; chunk < NP/64; ++chunk) {
        const int j = chunk*64 + lane;
        const float4 pj = *(const float4*)(xyzp + ((size_t)b*NP + j)*4);
        const float dx = xi - pj.x;
        const float dy = yi - pj.y;
        const float dx2 = dx*dx;
        const float dy2 = dy*dy;
        const float d2  = dx2 + dy2;
        const bool hit = (d2 < R2);
        const unsigned long long m = __ballot(hit);
        const int before = __popcll(m & ((1ULL << lane) - 1ULL));
        if (hit && (cnt + before) < KNN) orow[cnt + before] = j;
        cnt += __popcll(m);
        if (cnt >= KNN) break;
    }
    // pad remaining slots with self index (uniform cnt across the wave)
    for (int kk = cnt + lane; kk < KNN; kk += 64) orow[kk] = i;
}

// ---------------- K1: per-block speed partial sums ----------------
__global__ __launch_bounds__(256) void k_speedsum(const float* __restrict__ xyzp,
                                                  const int* __restrict__ idx,
                                                  double* __restrict__ spart)
{
    const int p = blockIdx.x*256 + threadIdx.x;     // pair id 0..262143
    const int b = p >> 17;                          // 131072 pairs/batch
    const int n = (p >> 5) & (NP - 1);
    const int j = idx[p];
    const float4 pi = *(const float4*)(xyzp + ((size_t)b*NP + n)*4);
    const float4 pj = *(const float4*)(xyzp + ((size_t)b*NP + j)*4);
    const float dx = pi.x - pj.x;
    const float dy = pi.y - pj.y;
    const float dz = pi.z - pj.z;
    const float ts = (dz == 0.0f) ? 1e-6f : dz;
    float sxv = dx / ts * 640.0f;
    float syv = dy / ts * 480.0f;
    #pragma unroll
    for (int off = 32; off > 0; off >>= 1) {
        sxv += __shfl_down(sxv, off);
        syv += __shfl_down(syv, off);
    }
    __shared__ float wr[4][2];
    const int w = threadIdx.x >> 6;
    if ((threadIdx.x & 63) == 0) { wr[w][0] = sxv; wr[w][1] = syv; }
    __syncthreads();
    if (threadIdx.x == 0) {
        double s0 = ((double)wr[0][0] + (double)wr[1][0]) + ((double)wr[2][0] + (double)wr[3][0]);
        double s1 = ((double)wr[0][1] + (double)wr[1][1]) + ((double)wr[2][1] + (double)wr[3][1]);
        spart[(size_t)blockIdx.x*2 + 0] = s0;
        spart[(size_t)blockIdx.x*2 + 1] = s1;
    }
}

// ---------------- K2: mean_speed + constant channel vector c[b] ----------------
__global__ __launch_bounds__(256) void k_meanspeed(const double* __restrict__ spart,
                                                   const float* __restrict__ Wm,
                                                   const float* __restrict__ bbias,
                                                   float* __restrict__ cvec)
{
    __shared__ double ms[2][2];
    const int t = threadIdx.x;
    const int grp = t >> 6, lane = t & 63;
    const int b = grp >> 1, comp = grp & 1;
    double s = 0.0;
    for (int q = lane; q < 512; q += 64)
        s += spart[(size_t)(b*512 + q)*2 + comp];
    #pragma unroll
    for (int off = 32; off > 0; off >>= 1) s += __shfl_down(s, off);
    if (lane == 0) ms[b][comp] = s / (double)(NP*KNN);
    __syncthreads();
    const int b2 = t >> 7, c = t & 127;
    const float msx = (float)ms[b2][0];
    const float msy = (float)ms[b2][1];
    cvec[b2*DIMC + c] = bbias[c] + msx*Wm[263*DIMC + c] + msy*Wm[264*DIMC + c];
}

// ---------------- K3: e = feat@W0, g = feat@W1 (small GEMM) ----------------
__global__ __launch_bounds__(256) void k_eg(const float* __restrict__ feat,
                                            const float* __restrict__ Wm,
                                            float* __restrict__ e, float* __restrict__ g)
{
    __shared__ float sf[16][DIMC];
    const int row0 = blockIdx.x * 16;
    for (int t = threadIdx.x; t < 16*DIMC; t += 256)
        ((float*)sf)[t] = feat[(size_t)row0*DIMC + t];
    __syncthreads();
    const int c = threadIdx.x;
    const int isg = c >> 7, cc = c & 127;
    const float* wcol = Wm + (size_t)(isg ? 128 : 0)*DIMC + cc;
    float acc[16];
    #pragma unroll
    for (int r = 0; r < 16; ++r) acc[r] = 0.0f;
    for (int kk = 0; kk < DIMC; ++kk) {
        const float w = wcol[(size_t)kk*DIMC];
        #pragma unroll
        for (int r = 0; r < 16; ++r) acc[r] = fmaf(sf[r][kk], w, acc[r]);
    }
    float* dst = isg ? g : e;
    #pragma unroll
    for (int r = 0; r < 16; ++r) dst[(size_t)(row0 + r)*DIMC + cc] = acc[r];
}

// ---------------- K4: per-pair h, min/max over K, stat partials ----------------
__global__ __launch_bounds__(256) void k_main(const float* __restrict__ xyzp,
                                              const int* __restrict__ idx,
                                              const float* __restrict__ e,
                                              const float* __restrict__ g,
                                              const float* __restrict__ Wm,
                                              const float* __restrict__ cvec,
                                              float* __restrict__ hmaxA,
                                              float* __restrict__ hminA,
                                              float* __restrict__ stpart)
{
    __shared__ float l1[4][DIMC];
    __shared__ float l2[4][DIMC];
    const int w    = threadIdx.x >> 6;
    const int lane = threadIdx.x & 63;
    const int c0   = lane*2;
    const int row_base = blockIdx.x * 8;
    const int b = row_base >> 12;              // 4096 rows per batch, 8 | 4096

    float w2a[7], w2b[7];
    #pragma unroll
    for (int r = 0; r < 7; ++r) {
        w2a[r] = Wm[(256 + r)*DIMC + c0];
        w2b[r] = Wm[(256 + r)*DIMC + c0 + 1];
    }
    const float cva = cvec[b*DIMC + c0];
    const float cvb = cvec[b*DIMC + c0 + 1];

    float s1a = 0.f, s1b = 0.f, s2a = 0.f, s2b = 0.f;

    for (int rr = 0; rr < 2; ++rr) {
        const int row = row_base + w*2 + rr;
        const float2 ee = *(const float2*)(e + (size_t)row*DIMC + c0);
        const float4 pi = *(const float4*)(xyzp + (size_t)row*4);
        const int* irow = idx + (size_t)row*KNN;
        float mxa = -INFINITY, mxb = -INFINITY, mna = INFINITY, mnb = INFINITY;
        for (int k = 0; k < KNN; ++k) {
            const int j = irow[k];
            const float4 pj = *(const float4*)(xyzp + ((size_t)b*NP + j)*4);
            const float dx  = pi.x - pj.x;
            const float dy  = pi.y - pj.y;
            const float dz  = pi.z - pj.z;
            const float dwv = pi.w - pj.w;
            const float ts  = (dz == 0.0f) ? 1e-6f : dz;
            const float sxv = dx/ts*640.0f;
            const float syv = dy/ts*480.0f;
            const float pa  = fabsf(dwv);
            const float2 gg = *(const float2*)(g + ((size_t)b*NP + j)*DIMC + c0);
            float ha = ee.x + gg.x + cva;
            float hb = ee.y + gg.y + cvb;
            ha = fmaf(dx,  w2a[0], ha); hb = fmaf(dx,  w2b[0], hb);
            ha = fmaf(dy,  w2a[1], ha); hb = fmaf(dy,  w2b[1], hb);
            ha = fmaf(dz,  w2a[2], ha); hb = fmaf(dz,  w2b[2], hb);
            ha = fmaf(dwv, w2a[3], ha); hb = fmaf(dwv, w2b[3], hb);
            ha = fmaf(sxv, w2a[4], ha); hb = fmaf(sxv, w2b[4], hb);
            ha = fmaf(syv, w2a[5], ha); hb = fmaf(syv, w2b[5], hb);
            ha = fmaf(pa,  w2a[6], ha); hb = fmaf(pa,  w2b[6], hb);
            mxa = fmaxf(mxa, ha); mna = fminf(mna, ha);
            mxb = fmaxf(mxb, hb); mnb = fminf(mnb, hb);
            s1a += ha; s2a = fmaf(ha, ha, s2a);
            s1b += hb; s2b = fmaf(hb, hb, s2b);
        }
        *(float2*)(hmaxA + (size_t)row*DIMC + c0) = make_float2(mxa, mxb);
        *(float2*)(hminA + (size_t)row*DIMC + c0) = make_float2(mna, mnb);
    }

    l1[w][c0] = s1a; l1[w][c0+1] = s1b;
    l2[w][c0] = s2a; l2[w][c0+1] = s2b;
    __syncthreads();
    const int t = threadIdx.x;
    if (t < DIMC) {
        float v = ((l1[0][t] + l1[1][t]) + l1[2][t]) + l1[3][t];
        stpart[(size_t)blockIdx.x*256 + t] = v;
    } else {
        const int tc = t - DIMC;
        float v = ((l2[0][tc] + l2[1][tc]) + l2[2][tc]) + l2[3][tc];
        stpart[(size_t)blockIdx.x*256 + t] = v;
    }
}

// ---------------- K5: deterministic reduce of stat partials ----------------
__global__ __launch_bounds__(256) void k_statreduce(const float* __restrict__ stpart,
                                                    double* __restrict__ sums)
{
    __shared__ double red[256];
    const int col = blockIdx.x;                 // 0..255 (128 sum, 128 sumsq)
    double s = 0.0;
    for (int q = threadIdx.x; q < 1024; q += 256)
        s += (double)stpart[(size_t)q*256 + col];
    red[threadIdx.x] = s;
    __syncthreads();
    for (int st = 128; st > 0; st >>= 1) {
        if (threadIdx.x < st) red[threadIdx.x] += red[threadIdx.x + st];
        __syncthreads();
    }
    if (threadIdx.x == 0) sums[col] = red[0];
}

// ---------------- K5b: per-channel affine coefficients ----------------
__global__ __launch_bounds__(128) void k_scale(const double* __restrict__ sums,
                                               const float* __restrict__ gamma,
                                               const float* __restrict__ beta,
                                               float* __restrict__ abuf,
                                               float* __restrict__ dbuf)
{
    const int c = threadIdx.x;
    const double M   = (double)MTOT;
    const double mu  = sums[c] / M;
    const double var = sums[DIMC + c] / M - mu*mu;
    const double inv = 1.0 / sqrt(var + 1e-5);
    const float a = (float)((double)gamma[c] * inv);
    abuf[c] = a;
    dbuf[c] = beta[c] - (float)mu * a;
}

// ---------------- K6: final normalize + relu + (pre-reduced) max over K ----------------
__global__ __launch_bounds__(256) void k_out(const float* __restrict__ hmaxA,
                                             const float* __restrict__ hminA,
                                             const float* __restrict__ abuf,
                                             const float* __restrict__ dbuf,
                                             float* __restrict__ out)
{
    const int gid = blockIdx.x*256 + threadIdx.x;   // 0..524287, 2 channels each
    const int row = gid >> 6;
    const int c0  = (gid & 63)*2;
    const size_t off = (size_t)row*DIMC + c0;
    const float2 mx = *(const float2*)(hmaxA + off);
    const float2 mn = *(const float2*)(hminA + off);
    const float a0 = abuf[c0],   a1 = abuf[c0+1];
    const float d0 = dbuf[c0],   d1 = dbuf[c0+1];
    const float h0 = (a0 >= 0.f) ? mx.x : mn.x;
    const float h1 = (a1 >= 0.f) ? mx.y : mn.y;
    float2 o;
    o.x = fmaxf(fmaf(h0, a0, d0), 0.0f);
    o.y = fmaxf(fmaf(h1, a1, d1), 0.0f);
    *(float2*)(out + off) = o;
}

extern "C" void kernel_launch(void* const* d_in, const int* in_sizes, int n_in,
                              void* d_out, int out_size, void* d_ws, size_t ws_size,
                              hipStream_t stream)
{
    const float* xyzp  = (const float*)d_in[0];
    const float* feat  = (const float*)d_in[1];
    const float* Wm    = (const float*)d_in[2];
    const float* bbias = (const float*)d_in[3];
    const float* gamma = (const float*)d_in[4];
    const float* beta  = (const float*)d_in[5];

    char* ws = (char*)d_ws;
    const size_t MB = 1u << 20;
    int*    idx    = (int*)   (ws + 0);            // 1 MB
    float*  g      = (float*) (ws + 1*MB);         // 4 MB
    float*  e      = (float*) (ws + 5*MB);         // 4 MB
    float*  hmaxA  = (float*) (ws + 9*MB);         // 4 MB
    float*  hminA  = (float*) (ws + 13*MB);        // 4 MB
    float*  cvec   = (float*) (ws + 17*MB);        // 1 KB
    double* sppart = (double*)(ws + 17*MB + 8192); // 16 KB
    float*  abuf   = (float*) (ws + 17*MB + 65536);
    float*  dbuf   = (float*) (ws + 17*MB + 65536 + 1024);
    float*  stpart = (float*) (ws + 18*MB);        // 1 MB
    double* sums   = (double*)(ws + 19*MB);        // 2 KB

    k_ballquery <<<NROWS/4, 256, 0, stream>>>(xyzp, idx);
    k_speedsum  <<<MTOT/256, 256, 0, stream>>>(xyzp, idx, sppart);
    k_meanspeed <<<1, 256, 0, stream>>>(sppart, Wm, bbias, cvec);
    k_eg        <<<NROWS/16, 256, 0, stream>>>(feat, Wm, e, g);
    k_main      <<<NROWS/8, 256, 0, stream>>>(xyzp, idx, e, g, Wm, cvec, hmaxA, hminA, stpart);
    k_statreduce<<<256, 256, 0, stream>>>(stpart, sums);
    k_scale     <<<1, 128, 0, stream>>>(sums, gamma, beta, abuf, dbuf);
    k_out       <<<(NROWS*64)/256, 256, 0, stream>>>(hmaxA, hminA, abuf, dbuf, (float*)d_out);
}

// Round 2
// 85.088 us; speedup vs baseline: 1.0868x; 1.0868x over previous
//
#include <hip/hip_runtime.h>
#include <math.h>

#define NB   2
#define NP   4096
#define KNN  32
#define DIMC 128
#define NROWS (NB*NP)          // 8192
#define MTOT  (NB*NP*KNN)      // 262144
#define QBLOCKS (NROWS/4)      // 2048 (ball query, 4 pts/block)
#define EGBLOCKS (NROWS/16)    // 512  (e/g GEMM, 16 rows/block)
#define MAINBLOCKS (NROWS/8)   // 1024

static constexpr float R2 = 0.04f;

// ---------------- kA (fat): ball query + speed partials | e/g GEMM ----------------
__global__ __launch_bounds__(256) void kA(const float* __restrict__ xyzp,
                                          const float* __restrict__ feat,
                                          const float* __restrict__ Wm,
                                          int* __restrict__ idx,
                                          double* __restrict__ spart,
                                          float* __restrict__ e,
                                          float* __restrict__ g)
{
    if (blockIdx.x < QBLOCKS) {
#pragma clang fp contract(off)
        __shared__ int   nl[4][KNN];
        __shared__ float swr[4][2];
        const int w    = threadIdx.x >> 6;
        const int lane = threadIdx.x & 63;
        const int pt   = blockIdx.x * 4 + w;      // global row 0..8191
        const int b    = pt >> 12;
        const int i    = pt & (NP - 1);
        const float* xb = xyzp + (size_t)b*NP*4;

        const float xi = xyzp[(size_t)pt*4 + 0];
        const float yi = xyzp[(size_t)pt*4 + 1];

        int cnt = 0;
        for (int chunk = 0; chunk < NP/64; ++chunk) {
            const int j = chunk*64 + lane;
            const float4 pj = *(const float4*)(xb + (size_t)j*4);
            const float dx = xi - pj.x;
            const float dy = yi - pj.y;
            const float dx2 = dx*dx;
            const float dy2 = dy*dy;
            const bool hit = (dx2 + dy2) < R2;
            const unsigned long long m = __ballot(hit);
            const int before = __popcll(m & ((1ULL << lane) - 1ULL));
            if (hit && (cnt + before) < KNN) nl[w][cnt + before] = j;
            cnt += __popcll(m);
            if (cnt >= KNN) break;
        }
        for (int kk = cnt + lane; kk < KNN; kk += 64) nl[w][kk] = i;
        __syncthreads();

        float sxv = 0.f, syv = 0.f;
        if (lane < KNN) {
            const int j = nl[w][lane];
            idx[(size_t)pt*KNN + lane] = j;                  // coalesced 128B store
            const float4 pj = *(const float4*)(xb + (size_t)j*4);
            const float4 pi = *(const float4*)(xyzp + (size_t)pt*4);
            const float dz = pi.z - pj.z;
            const float ts = (dz == 0.f) ? 1e-6f : dz;
            const float rts = __builtin_amdgcn_rcpf(ts);
            sxv = (pi.x - pj.x)*rts*640.f;
            syv = (pi.y - pj.y)*rts*480.f;
        }
        #pragma unroll
        for (int off = 32; off > 0; off >>= 1) {
            sxv += __shfl_down(sxv, off);
            syv += __shfl_down(syv, off);
        }
        if (lane == 0) { swr[w][0] = sxv; swr[w][1] = syv; }
        __syncthreads();
        if (threadIdx.x == 0) {
            double s0 = ((double)swr[0][0] + (double)swr[1][0]) + ((double)swr[2][0] + (double)swr[3][0]);
            double s1 = ((double)swr[0][1] + (double)swr[1][1]) + ((double)swr[2][1] + (double)swr[3][1]);
            spart[(size_t)blockIdx.x*2 + 0] = s0;
            spart[(size_t)blockIdx.x*2 + 1] = s1;
        }
    } else {
        // ---- e = feat@W0, g = feat@W1 ----
        __shared__ float sf[16][DIMC];
        const int row0 = (blockIdx.x - QBLOCKS) * 16;
        for (int t = threadIdx.x; t < 16*DIMC; t += 256)
            ((float*)sf)[t] = feat[(size_t)row0*DIMC + t];
        __syncthreads();
        const int c = threadIdx.x;
        const int isg = c >> 7, cc = c & 127;
        const float* wcol = Wm + (size_t)(isg ? 128 : 0)*DIMC + cc;
        float acc[16];
        #pragma unroll
        for (int r = 0; r < 16; ++r) acc[r] = 0.0f;
        for (int kk = 0; kk < DIMC; ++kk) {
            const float w = wcol[(size_t)kk*DIMC];
            #pragma unroll
            for (int r = 0; r < 16; ++r) acc[r] = fmaf(sf[r][kk], w, acc[r]);
        }
        float* dst = isg ? g : e;
        #pragma unroll
        for (int r = 0; r < 16; ++r) dst[(size_t)(row0 + r)*DIMC + cc] = acc[r];
    }
}

// ---------------- kD: per-pair h, min/max over K, transposed stat partials ----------------
__global__ __launch_bounds__(256) void kD(const float* __restrict__ xyzp,
                                          const int* __restrict__ idx,
                                          const float* __restrict__ e,
                                          const float* __restrict__ g,
                                          const float* __restrict__ Wm,
                                          const float* __restrict__ bbias,
                                          const double* __restrict__ spart,
                                          float* __restrict__ hmaxA,
                                          float* __restrict__ hminA,
                                          float* __restrict__ stpartT)
{
    __shared__ float  geo[4][KNN][8];
    __shared__ double rsp[256][2];
    __shared__ float  msS[2];
    __shared__ float  l1[4][DIMC], l2[4][DIMC];

    const int t        = threadIdx.x;
    const int row_base = blockIdx.x * 8;
    const int b        = row_base >> 12;

    // --- per-block mean_speed reduction (8 KB, deterministic fixed order) ---
    {
        double sx = 0.0, sy = 0.0;
        const double* sp = spart + (size_t)b * 2048;   // 1024 blocks x double2
        for (int q = t; q < 1024; q += 256) { sx += sp[q*2]; sy += sp[q*2+1]; }
        rsp[t][0] = sx; rsp[t][1] = sy;
        __syncthreads();
        for (int st = 128; st > 0; st >>= 1) {
            if (t < st) { rsp[t][0] += rsp[t+st][0]; rsp[t][1] += rsp[t+st][1]; }
            __syncthreads();
        }
        if (t == 0) {
            msS[0] = (float)(rsp[0][0] / (double)(NP*KNN));
            msS[1] = (float)(rsp[0][1] / (double)(NP*KNN));
        }
        __syncthreads();
    }

    const int w    = t >> 6;
    const int lane = t & 63;
    const int c0   = lane * 2;
    const float msx = msS[0], msy = msS[1];

    float w2a[7], w2b[7];
    #pragma unroll
    for (int r = 0; r < 7; ++r) {
        w2a[r] = Wm[(256 + r)*DIMC + c0];
        w2b[r] = Wm[(256 + r)*DIMC + c0 + 1];
    }
    const float cva = fmaf(msx, Wm[263*DIMC + c0],     fmaf(msy, Wm[264*DIMC + c0],     bbias[c0]));
    const float cvb = fmaf(msx, Wm[263*DIMC + c0 + 1], fmaf(msy, Wm[264*DIMC + c0 + 1], bbias[c0+1]));

    const float* gb = g + (size_t)b*NP*DIMC + c0;
    float s1a = 0.f, s1b = 0.f, s2a = 0.f, s2b = 0.f;

    for (int rr = 0; rr < 2; ++rr) {
        const int row = row_base + w*2 + rr;
        // lanes 0..31: compute pair geometry once, stash in LDS (8 floats incl. j)
        if (lane < KNN) {
            const int j = idx[(size_t)row*KNN + lane];
            const float4 pj = *(const float4*)(xyzp + ((size_t)b*NP + j)*4);
            const float4 pi = *(const float4*)(xyzp + (size_t)row*4);
            const float dx = pi.x - pj.x;
            const float dy = pi.y - pj.y;
            const float dz = pi.z - pj.z;
            const float dwv = pi.w - pj.w;
            const float ts  = (dz == 0.f) ? 1e-6f : dz;
            const float rts = __builtin_amdgcn_rcpf(ts);
            geo[w][lane][0] = dx;
            geo[w][lane][1] = dy;
            geo[w][lane][2] = dz;
            geo[w][lane][3] = dwv;
            geo[w][lane][4] = dx*rts*640.f;
            geo[w][lane][5] = dy*rts*480.f;
            geo[w][lane][6] = fabsf(dwv);
            geo[w][lane][7] = __int_as_float(j);
        }
        __syncthreads();

        const float2 ee = *(const float2*)(e + (size_t)row*DIMC + c0);
        float mxa = -INFINITY, mxb = -INFINITY, mna = INFINITY, mnb = INFINITY;
        #pragma unroll 4
        for (int k = 0; k < KNN; ++k) {
            const float4 g0 = *(const float4*)&geo[w][k][0];   // broadcast ds_read_b128
            const float4 g1 = *(const float4*)&geo[w][k][4];
            const int j = __float_as_int(g1.w);
            const float2 gg = *(const float2*)(gb + (size_t)j*DIMC);
            float ha = ee.x + gg.x + cva;
            float hb = ee.y + gg.y + cvb;
            ha = fmaf(g0.x, w2a[0], ha); hb = fmaf(g0.x, w2b[0], hb);
            ha = fmaf(g0.y, w2a[1], ha); hb = fmaf(g0.y, w2b[1], hb);
            ha = fmaf(g0.z, w2a[2], ha); hb = fmaf(g0.z, w2b[2], hb);
            ha = fmaf(g0.w, w2a[3], ha); hb = fmaf(g0.w, w2b[3], hb);
            ha = fmaf(g1.x, w2a[4], ha); hb = fmaf(g1.x, w2b[4], hb);
            ha = fmaf(g1.y, w2a[5], ha); hb = fmaf(g1.y, w2b[5], hb);
            ha = fmaf(g1.z, w2a[6], ha); hb = fmaf(g1.z, w2b[6], hb);
            mxa = fmaxf(mxa, ha); mna = fminf(mna, ha);
            mxb = fmaxf(mxb, hb); mnb = fminf(mnb, hb);
            s1a += ha; s2a = fmaf(ha, ha, s2a);
            s1b += hb; s2b = fmaf(hb, hb, s2b);
        }
        *(float2*)(hmaxA + (size_t)row*DIMC + c0) = make_float2(mxa, mxb);
        *(float2*)(hminA + (size_t)row*DIMC + c0) = make_float2(mna, mnb);
        __syncthreads();   // geo reused next rr
    }

    l1[w][c0] = s1a; l1[w][c0+1] = s1b;
    l2[w][c0] = s2a; l2[w][c0+1] = s2b;
    __syncthreads();
    if (t < DIMC) {
        const float v = ((l1[0][t] + l1[1][t]) + l1[2][t]) + l1[3][t];
        stpartT[(size_t)t*MAINBLOCKS + blockIdx.x] = v;
    } else {
        const int tc = t - DIMC;
        const float v = ((l2[0][tc] + l2[1][tc]) + l2[2][tc]) + l2[3][tc];
        stpartT[(size_t)t*MAINBLOCKS + blockIdx.x] = v;
    }
}

// ---------------- kE: coalesced stat reduce + affine coefficients ----------------
__global__ __launch_bounds__(256) void kE(const float* __restrict__ stpartT,
                                          const float* __restrict__ gamma,
                                          const float* __restrict__ beta,
                                          float* __restrict__ abuf,
                                          float* __restrict__ dbuf)
{
    const int c = blockIdx.x;          // 0..127
    const int t = threadIdx.x;
    double s1 = 0.0, s2 = 0.0;
    for (int q = t; q < MAINBLOCKS; q += 256) {
        s1 += (double)stpartT[(size_t)c*MAINBLOCKS + q];
        s2 += (double)stpartT[(size_t)(c + DIMC)*MAINBLOCKS + q];
    }
    __shared__ double r1[256], r2[256];
    r1[t] = s1; r2[t] = s2;
    __syncthreads();
    for (int st = 128; st > 0; st >>= 1) {
        if (t < st) { r1[t] += r1[t+st]; r2[t] += r2[t+st]; }
        __syncthreads();
    }
    if (t == 0) {
        const double M   = (double)MTOT;
        const double mu  = r1[0] / M;
        const double var = r2[0] / M - mu*mu;
        const double inv = 1.0 / sqrt(var + 1e-5);
        const float a = (float)((double)gamma[c] * inv);
        abuf[c] = a;
        dbuf[c] = beta[c] - (float)mu * a;
    }
}

// ---------------- kF: normalize + relu on the pre-reduced K-extremes ----------------
__global__ __launch_bounds__(256) void kF(const float* __restrict__ hmaxA,
                                          const float* __restrict__ hminA,
                                          const float* __restrict__ abuf,
                                          const float* __restrict__ dbuf,
                                          float* __restrict__ out)
{
    const int gid = blockIdx.x*256 + threadIdx.x;   // 2 channels each
    const int row = gid >> 6;
    const int c0  = (gid & 63)*2;
    const size_t off = (size_t)row*DIMC + c0;
    const float2 mx = *(const float2*)(hmaxA + off);
    const float2 mn = *(const float2*)(hminA + off);
    const float a0 = abuf[c0],   a1 = abuf[c0+1];
    const float d0 = dbuf[c0],   d1 = dbuf[c0+1];
    const float h0 = (a0 >= 0.f) ? mx.x : mn.x;
    const float h1 = (a1 >= 0.f) ? mx.y : mn.y;
    float2 o;
    o.x = fmaxf(fmaf(h0, a0, d0), 0.0f);
    o.y = fmaxf(fmaf(h1, a1, d1), 0.0f);
    *(float2*)(out + off) = o;
}

extern "C" void kernel_launch(void* const* d_in, const int* in_sizes, int n_in,
                              void* d_out, int out_size, void* d_ws, size_t ws_size,
                              hipStream_t stream)
{
    const float* xyzp  = (const float*)d_in[0];
    const float* feat  = (const float*)d_in[1];
    const float* Wm    = (const float*)d_in[2];
    const float* bbias = (const float*)d_in[3];
    const float* gamma = (const float*)d_in[4];
    const float* beta  = (const float*)d_in[5];

    char* ws = (char*)d_ws;
    const size_t MB = 1u << 20;
    int*    idx     = (int*)   (ws + 0);             // 1 MB
    float*  g       = (float*) (ws + 1*MB);          // 4 MB
    float*  e       = (float*) (ws + 5*MB);          // 4 MB
    float*  hmaxA   = (float*) (ws + 9*MB);          // 4 MB
    float*  hminA   = (float*) (ws + 13*MB);         // 4 MB
    double* spart   = (double*)(ws + 17*MB);         // 32 KB (2048 x double2)
    float*  abuf    = (float*) (ws + 17*MB + 65536);
    float*  dbuf    = (float*) (ws + 17*MB + 65536 + 1024);
    float*  stpartT = (float*) (ws + 18*MB);         // 1 MB (256 x 1024)

    kA <<<QBLOCKS + EGBLOCKS, 256, 0, stream>>>(xyzp, feat, Wm, idx, spart, e, g);
    kD <<<MAINBLOCKS, 256, 0, stream>>>(xyzp, idx, e, g, Wm, bbias, spart, hmaxA, hminA, stpartT);
    kE <<<DIMC, 256, 0, stream>>>(stpartT, gamma, beta, abuf, dbuf);
    kF <<<(NROWS*64)/256, 256, 0, stream>>>(hmaxA, hminA, abuf, dbuf, (float*)d_out);
}

// Round 3
// 58.471 us; speedup vs baseline: 1.5816x; 1.4552x over previous
//
#include <hip/hip_runtime.h>
#include <math.h>

#define NB   2
#define NP   4096
#define KNN  32
#define DIMC 128
#define NROWS (NB*NP)          // 8192
#define MTOT  (NB*NP*KNN)      // 262144
#define MASKBLOCKS 512         // 16 points each (4 per wave)
#define EGBLOCKS   512         // 16 rows each
#define MAINBLOCKS (NROWS/8)   // 1024

static constexpr float R2 = 0.04f;

// ---------------- kB (fat): {mask-build + extract + speed partials} | {e/g GEMM} ----------------
__global__ __launch_bounds__(256) void kB(const float* __restrict__ xyzp,
                                          const float* __restrict__ feat,
                                          const float* __restrict__ Wm,
                                          int* __restrict__ idx,
                                          double* __restrict__ spart,
                                          float* __restrict__ e,
                                          float* __restrict__ g)
{
    __shared__ float smem[NP*2 + 16*KNN + 8];   // 32KB xy | idxrow | swr  (34.1KB)

    if (blockIdx.x < MASKBLOCKS) {
#pragma clang fp contract(off)
        float* xy     = smem;                       // [4096][2]
        int*   idxrow = (int*)(smem + NP*2);        // [16][32]
        float* swr    = smem + NP*2 + 16*KNN;       // [4][2]

        const int t    = threadIdx.x;
        const int w    = t >> 6;
        const int lane = t & 63;
        const int b    = blockIdx.x >> 8;           // 256 blocks per batch
        const int p0   = (blockIdx.x & 255) * 16;   // local point base
        const float* xb = xyzp + (size_t)b*NP*4;

        // stage this batch's xy into LDS (coalesced float4 loads)
        for (int q = t; q < NP; q += 256) {
            const float4 v = *(const float4*)(xb + (size_t)q*4);
            xy[q*2 + 0] = v.x;
            xy[q*2 + 1] = v.y;
        }
        __syncthreads();

        // 4 points per wave; 64 independent chunks, no early exit
        const int pl0 = p0 + w*4;
        float xi[4], yi[4];
        #pragma unroll
        for (int p = 0; p < 4; ++p) { xi[p] = xy[(pl0+p)*2]; yi[p] = xy[(pl0+p)*2+1]; }

        unsigned long long wacc[4] = {0ULL,0ULL,0ULL,0ULL};
        for (int c = 0; c < NP/64; ++c) {
            const float2 q = *(const float2*)(xy + (size_t)(c*64 + lane)*2);
            #pragma unroll
            for (int p = 0; p < 4; ++p) {
                const float dx = xi[p] - q.x;
                const float dy = yi[p] - q.y;
                const float dx2 = dx*dx;
                const float dy2 = dy*dy;
                const unsigned long long m = __ballot((dx2 + dy2) < R2);
                if (lane == c) wacc[p] = m;       // lane l keeps word l
            }
        }

        // in-register extraction: first 32 set bits in ascending j order
        #pragma unroll
        for (int p = 0; p < 4; ++p) {
            unsigned long long wd = wacc[p];
            const int cnt = __popcll(wd);
            int pre = cnt;                          // inclusive prefix over lanes
            #pragma unroll
            for (int off = 1; off < 64; off <<= 1) {
                const int tv = __shfl_up(pre, off);
                if (lane >= off) pre += tv;
            }
            const int total = __shfl(pre, 63);
            int slot = pre - cnt;                   // exclusive prefix
            unsigned long long ww = wd;
            while (ww != 0ULL && slot < KNN) {
                const int bpos = __builtin_ctzll(ww);
                idxrow[(w*4 + p)*KNN + slot] = lane*64 + bpos;
                ww &= ww - 1ULL;
                ++slot;
            }
            const int iself = pl0 + p;              // self-pad (local index)
            for (int kk = min(total, KNN) + lane; kk < KNN; kk += 64)
                idxrow[(w*4 + p)*KNN + kk] = iself;
        }
        __syncthreads();

        // speed partial sums + global idx store
        float sxa = 0.f, sya = 0.f;
        #pragma unroll
        for (int p = 0; p < 4; ++p) {
            const int pt = b*NP + pl0 + p;
            float sxv = 0.f, syv = 0.f;
            if (lane < KNN) {
                const int j = idxrow[(w*4 + p)*KNN + lane];
                idx[(size_t)pt*KNN + lane] = j;
                const float4 pj = *(const float4*)(xb + (size_t)j*4);
                const float4 pi = *(const float4*)(xyzp + (size_t)pt*4);
                const float dz = pi.z - pj.z;
                const float ts = (dz == 0.f) ? 1e-6f : dz;
                const float rts = __builtin_amdgcn_rcpf(ts);
                sxv = (pi.x - pj.x)*rts*640.f;
                syv = (pi.y - pj.y)*rts*480.f;
            }
            sxa += sxv; sya += syv;
        }
        #pragma unroll
        for (int off = 32; off > 0; off >>= 1) {
            sxa += __shfl_down(sxa, off);
            sya += __shfl_down(sya, off);
        }
        if (lane == 0) { swr[w*2] = sxa; swr[w*2+1] = sya; }
        __syncthreads();
        if (t == 0) {
            const double s0 = ((double)swr[0] + (double)swr[2]) + ((double)swr[4] + (double)swr[6]);
            const double s1 = ((double)swr[1] + (double)swr[3]) + ((double)swr[5] + (double)swr[7]);
            spart[(size_t)blockIdx.x*2 + 0] = s0;
            spart[(size_t)blockIdx.x*2 + 1] = s1;
        }
    } else {
        // ---- e = feat@W0, g = feat@W1 ----
        float (*sf)[DIMC] = (float (*)[DIMC])smem;
        const int row0 = (blockIdx.x - MASKBLOCKS) * 16;
        for (int t = threadIdx.x; t < 16*DIMC; t += 256)
            ((float*)sf)[t] = feat[(size_t)row0*DIMC + t];
        __syncthreads();
        const int c = threadIdx.x;
        const int isg = c >> 7, cc = c & 127;
        const float* wcol = Wm + (size_t)(isg ? 128 : 0)*DIMC + cc;
        float acc[16];
        #pragma unroll
        for (int r = 0; r < 16; ++r) acc[r] = 0.0f;
        for (int kk = 0; kk < DIMC; ++kk) {
            const float w = wcol[(size_t)kk*DIMC];
            #pragma unroll
            for (int r = 0; r < 16; ++r) acc[r] = fmaf(sf[r][kk], w, acc[r]);
        }
        float* dst = isg ? g : e;
        #pragma unroll
        for (int r = 0; r < 16; ++r) dst[(size_t)(row0 + r)*DIMC + cc] = acc[r];
    }
}

// ---------------- kD: per-pair h, min/max over K, transposed stat partials ----------------
__global__ __launch_bounds__(256) void kD(const float* __restrict__ xyzp,
                                          const int* __restrict__ idx,
                                          const float* __restrict__ e,
                                          const float* __restrict__ g,
                                          const float* __restrict__ Wm,
                                          const float* __restrict__ bbias,
                                          const double* __restrict__ spart,
                                          float* __restrict__ hmaxA,
                                          float* __restrict__ hminA,
                                          float* __restrict__ stpartT)
{
    __shared__ float  geo[4][KNN][8];
    __shared__ double rsp[256][2];
    __shared__ float  msS[2];
    __shared__ float  l1[4][DIMC], l2[4][DIMC];

    const int t        = threadIdx.x;
    const int row_base = blockIdx.x * 8;
    const int b        = row_base >> 12;

    // per-block mean_speed re-reduction (256 double2 entries, fixed order)
    {
        const double* sp = spart + (size_t)b * 512;
        rsp[t][0] = sp[t*2];
        rsp[t][1] = sp[t*2 + 1];
        __syncthreads();
        for (int st = 128; st > 0; st >>= 1) {
            if (t < st) { rsp[t][0] += rsp[t+st][0]; rsp[t][1] += rsp[t+st][1]; }
            __syncthreads();
        }
        if (t == 0) {
            msS[0] = (float)(rsp[0][0] / (double)(NP*KNN));
            msS[1] = (float)(rsp[0][1] / (double)(NP*KNN));
        }
        __syncthreads();
    }

    const int w    = t >> 6;
    const int lane = t & 63;
    const int c0   = lane * 2;
    const float msx = msS[0], msy = msS[1];

    float w2a[7], w2b[7];
    #pragma unroll
    for (int r = 0; r < 7; ++r) {
        w2a[r] = Wm[(256 + r)*DIMC + c0];
        w2b[r] = Wm[(256 + r)*DIMC + c0 + 1];
    }
    const float cva = fmaf(msx, Wm[263*DIMC + c0],     fmaf(msy, Wm[264*DIMC + c0],     bbias[c0]));
    const float cvb = fmaf(msx, Wm[263*DIMC + c0 + 1], fmaf(msy, Wm[264*DIMC + c0 + 1], bbias[c0+1]));

    const float* gb = g + (size_t)b*NP*DIMC + c0;
    float s1a = 0.f, s1b = 0.f, s2a = 0.f, s2b = 0.f;

    for (int rr = 0; rr < 2; ++rr) {
        const int row = row_base + w*2 + rr;
        if (lane < KNN) {
            const int j = idx[(size_t)row*KNN + lane];
            const float4 pj = *(const float4*)(xyzp + ((size_t)b*NP + j)*4);
            const float4 pi = *(const float4*)(xyzp + (size_t)row*4);
            const float dx = pi.x - pj.x;
            const float dy = pi.y - pj.y;
            const float dz = pi.z - pj.z;
            const float dwv = pi.w - pj.w;
            const float ts  = (dz == 0.f) ? 1e-6f : dz;
            const float rts = __builtin_amdgcn_rcpf(ts);
            geo[w][lane][0] = dx;
            geo[w][lane][1] = dy;
            geo[w][lane][2] = dz;
            geo[w][lane][3] = dwv;
            geo[w][lane][4] = dx*rts*640.f;
            geo[w][lane][5] = dy*rts*480.f;
            geo[w][lane][6] = fabsf(dwv);
            geo[w][lane][7] = __int_as_float(j);
        }
        __syncthreads();

        const float2 ee = *(const float2*)(e + (size_t)row*DIMC + c0);
        float mxa = -INFINITY, mxb = -INFINITY, mna = INFINITY, mnb = INFINITY;
        #pragma unroll 4
        for (int k = 0; k < KNN; ++k) {
            const float4 g0 = *(const float4*)&geo[w][k][0];
            const float4 g1 = *(const float4*)&geo[w][k][4];
            const int j = __float_as_int(g1.w);
            const float2 gg = *(const float2*)(gb + (size_t)j*DIMC);
            float ha = ee.x + gg.x + cva;
            float hb = ee.y + gg.y + cvb;
            ha = fmaf(g0.x, w2a[0], ha); hb = fmaf(g0.x, w2b[0], hb);
            ha = fmaf(g0.y, w2a[1], ha); hb = fmaf(g0.y, w2b[1], hb);
            ha = fmaf(g0.z, w2a[2], ha); hb = fmaf(g0.z, w2b[2], hb);
            ha = fmaf(g0.w, w2a[3], ha); hb = fmaf(g0.w, w2b[3], hb);
            ha = fmaf(g1.x, w2a[4], ha); hb = fmaf(g1.x, w2b[4], hb);
            ha = fmaf(g1.y, w2a[5], ha); hb = fmaf(g1.y, w2b[5], hb);
            ha = fmaf(g1.z, w2a[6], ha); hb = fmaf(g1.z, w2b[6], hb);
            mxa = fmaxf(mxa, ha); mna = fminf(mna, ha);
            mxb = fmaxf(mxb, hb); mnb = fminf(mnb, hb);
            s1a += ha; s2a = fmaf(ha, ha, s2a);
            s1b += hb; s2b = fmaf(hb, hb, s2b);
        }
        *(float2*)(hmaxA + (size_t)row*DIMC + c0) = make_float2(mxa, mxb);
        *(float2*)(hminA + (size_t)row*DIMC + c0) = make_float2(mna, mnb);
        __syncthreads();
    }

    l1[w][c0] = s1a; l1[w][c0+1] = s1b;
    l2[w][c0] = s2a; l2[w][c0+1] = s2b;
    __syncthreads();
    if (t < DIMC) {
        const float v = ((l1[0][t] + l1[1][t]) + l1[2][t]) + l1[3][t];
        stpartT[(size_t)t*MAINBLOCKS + blockIdx.x] = v;
    } else {
        const int tc = t - DIMC;
        const float v = ((l2[0][tc] + l2[1][tc]) + l2[2][tc]) + l2[3][tc];
        stpartT[(size_t)t*MAINBLOCKS + blockIdx.x] = v;
    }
}

// ---------------- kE: coalesced stat reduce + affine coefficients ----------------
__global__ __launch_bounds__(256) void kE(const float* __restrict__ stpartT,
                                          const float* __restrict__ gamma,
                                          const float* __restrict__ beta,
                                          float* __restrict__ abuf,
                                          float* __restrict__ dbuf)
{
    const int c = blockIdx.x;          // 0..127
    const int t = threadIdx.x;
    double s1 = 0.0, s2 = 0.0;
    for (int q = t; q < MAINBLOCKS; q += 256) {
        s1 += (double)stpartT[(size_t)c*MAINBLOCKS + q];
        s2 += (double)stpartT[(size_t)(c + DIMC)*MAINBLOCKS + q];
    }
    __shared__ double r1[256], r2[256];
    r1[t] = s1; r2[t] = s2;
    __syncthreads();
    for (int st = 128; st > 0; st >>= 1) {
        if (t < st) { r1[t] += r1[t+st]; r2[t] += r2[t+st]; }
        __syncthreads();
    }
    if (t == 0) {
        const double M   = (double)MTOT;
        const double mu  = r1[0] / M;
        const double var = r2[0] / M - mu*mu;
        const double inv = 1.0 / sqrt(var + 1e-5);
        const float a = (float)((double)gamma[c] * inv);
        abuf[c] = a;
        dbuf[c] = beta[c] - (float)mu * a;
    }
}

// ---------------- kF: normalize + relu on the pre-reduced K-extremes ----------------
__global__ __launch_bounds__(256) void kF(const float* __restrict__ hmaxA,
                                          const float* __restrict__ hminA,
                                          const float* __restrict__ abuf,
                                          const float* __restrict__ dbuf,
                                          float* __restrict__ out)
{
    const int gid = blockIdx.x*256 + threadIdx.x;
    const int row = gid >> 6;
    const int c0  = (gid & 63)*2;
    const size_t off = (size_t)row*DIMC + c0;
    const float2 mx = *(const float2*)(hmaxA + off);
    const float2 mn = *(const float2*)(hminA + off);
    const float a0 = abuf[c0],   a1 = abuf[c0+1];
    const float d0 = dbuf[c0],   d1 = dbuf[c0+1];
    const float h0 = (a0 >= 0.f) ? mx.x : mn.x;
    const float h1 = (a1 >= 0.f) ? mx.y : mn.y;
    float2 o;
    o.x = fmaxf(fmaf(h0, a0, d0), 0.0f);
    o.y = fmaxf(fmaf(h1, a1, d1), 0.0f);
    *(float2*)(out + off) = o;
}

extern "C" void kernel_launch(void* const* d_in, const int* in_sizes, int n_in,
                              void* d_out, int out_size, void* d_ws, size_t ws_size,
                              hipStream_t stream)
{
    const float* xyzp  = (const float*)d_in[0];
    const float* feat  = (const float*)d_in[1];
    const float* Wm    = (const float*)d_in[2];
    const float* bbias = (const float*)d_in[3];
    const float* gamma = (const float*)d_in[4];
    const float* beta  = (const float*)d_in[5];

    char* ws = (char*)d_ws;
    const size_t MB = 1u << 20;
    int*    idx     = (int*)   (ws + 0);             // 1 MB
    float*  g       = (float*) (ws + 1*MB);          // 4 MB
    float*  e       = (float*) (ws + 5*MB);          // 4 MB
    float*  hmaxA   = (float*) (ws + 9*MB);          // 4 MB
    float*  hminA   = (float*) (ws + 13*MB);         // 4 MB
    double* spart   = (double*)(ws + 17*MB);         // 8 KB (512 x double2)
    float*  abuf    = (float*) (ws + 17*MB + 65536);
    float*  dbuf    = (float*) (ws + 17*MB + 65536 + 1024);
    float*  stpartT = (float*) (ws + 18*MB);         // 1 MB (256 x 1024)

    kB <<<MASKBLOCKS + EGBLOCKS, 256, 0, stream>>>(xyzp, feat, Wm, idx, spart, e, g);
    kD <<<MAINBLOCKS, 256, 0, stream>>>(xyzp, idx, e, g, Wm, bbias, spart, hmaxA, hminA, stpartT);
    kE <<<DIMC, 256, 0, stream>>>(stpartT, gamma, beta, abuf, dbuf);
    kF <<<(NROWS*64)/256, 256, 0, stream>>>(hmaxA, hminA, abuf, dbuf, (float*)d_out);
}